// Round 1
// baseline (1612.639 us; speedup 1.0000x reference)
//
#include <hip/hip_runtime.h>
#include <hip/hip_bf16.h>
#include <math.h>

// Problem dims (compile-time)
constexpr int NB = 64;     // batch
constexpr int NT = 30;     // decode steps
constexpr int NS = 31;     // encoder positions
constexpr int NE = 128;    // embedding dim
constexpr int NU = 256;    // hidden
constexpr int NV = 32000;  // vocab
constexpr int NG = 4 * NU;    // 1024 (gates)
constexpr int NCIN = NE + NU; // 384

__device__ __forceinline__ float sigmoidf_(float x) {
    return 1.0f / (1.0f + __expf(-x));
}

// ---------------------------------------------------------------------------
// keys[b,s,v] = sum_u memory[b,s,u] * W_mem[u,v]
// 8 rows per block so W_mem is read 248x total (not 1984x).
// ---------------------------------------------------------------------------
__global__ __launch_bounds__(256) void keys_kernel(
    const float* __restrict__ memory, const float* __restrict__ W_mem,
    float* __restrict__ keys) {
    const int row0 = blockIdx.x * 8;   // row = b*NS + s, 1984 rows total
    const int u = threadIdx.x;         // output column
    __shared__ float mS[8][NU];
#pragma unroll
    for (int r = 0; r < 8; ++r) mS[r][u] = memory[(row0 + r) * NU + u];
    __syncthreads();
    float acc[8] = {0, 0, 0, 0, 0, 0, 0, 0};
#pragma unroll 4
    for (int v = 0; v < NU; ++v) {
        float w = W_mem[v * NU + u];
#pragma unroll
        for (int r = 0; r < 8; ++r) acc[r] += mS[r][v] * w;
    }
#pragma unroll
    for (int r = 0; r < 8; ++r) keys[(row0 + r) * NU + u] = acc[r];
}

// ---------------------------------------------------------------------------
// Recurrence: one block per batch element, all 30 steps in-kernel.
// Produces attn_all[(b*NT + t)*NU + u] for the final big GEMM.
// ---------------------------------------------------------------------------
__global__ __launch_bounds__(256) void recurrence_kernel(
    const int* __restrict__ inputs,      // [NB,NT]
    const float* __restrict__ memory,    // [NB,NS,NU]
    const float* __restrict__ sample_h,  // [NB,NU]
    const float* __restrict__ sample_c,  // [NB,NU]
    const float* __restrict__ emb,       // [NV,NE]
    const float* __restrict__ W_k,       // [384,1024]
    const float* __restrict__ W_r,       // [256,1024]
    const float* __restrict__ b_lstm,    // [1024]
    const float* __restrict__ W_attn,    // [512,256]
    const float* __restrict__ keys,      // [NB,NS,NU]
    float* __restrict__ attn_all)        // [NB*NT,NU]
{
    const int b = blockIdx.x;
    const int tid = threadIdx.x;

    __shared__ float cinS[NCIN];  // [x_t, attn]
    __shared__ float hS[NU];
    __shared__ float zS[NG];
    __shared__ float ctxS[NU];
    __shared__ float spS[248];
    __shared__ float scS[NS];

    const float* keysb = keys + (size_t)b * NS * NU;
    const float* memb  = memory + (size_t)b * NS * NU;

    float c_reg = sample_c[b * NU + tid];
    hS[tid] = sample_h[b * NU + tid];
    float attn_reg = 0.0f;

    // z-phase mapping: thread owns gate g, 4 consecutive columns c4..c4+3
    const int g = tid >> 6;           // 0..3
    const int c4 = (tid & 63) << 2;   // 0..252
    const float* Wk4 = W_k + g * NU + c4;
    const float* Wr4 = W_r + g * NU + c4;
    const float4 bl = *(const float4*)(b_lstm + g * NU + c4);
    __syncthreads();

    for (int t = 0; t < NT; ++t) {
        // --- 1. stage cell_in = concat(x_t, attn_{t-1}) ---
        if (tid < NE) {
            int idx = inputs[b * NT + t];
            cinS[tid] = emb[(size_t)idx * NE + tid];
        }
        cinS[NE + tid] = attn_reg;
        __syncthreads();

        // --- 2. z = cell_in @ W_k + h @ W_r + b_lstm ---
        float4 acc = bl;
#pragma unroll 8
        for (int k = 0; k < NCIN; ++k) {
            float a = cinS[k];
            float4 w = *(const float4*)(Wk4 + (size_t)k * NG);
            acc.x += a * w.x; acc.y += a * w.y;
            acc.z += a * w.z; acc.w += a * w.w;
        }
#pragma unroll 8
        for (int k = 0; k < NU; ++k) {
            float a = hS[k];
            float4 w = *(const float4*)(Wr4 + (size_t)k * NG);
            acc.x += a * w.x; acc.y += a * w.y;
            acc.z += a * w.z; acc.w += a * w.w;
        }
        *(float4*)(zS + g * NU + c4) = acc;
        __syncthreads();

        // --- 3. LSTM gates (thread owns element u = tid) ---
        {
            float zi = zS[tid], zf = zS[NU + tid];
            float zg = zS[2 * NU + tid], zo = zS[3 * NU + tid];
            c_reg = sigmoidf_(zf) * c_reg + sigmoidf_(zi) * tanhf(zg);
            float h_new = sigmoidf_(zo) * tanhf(c_reg);
            hS[tid] = h_new;   // all phase-2 reads of hS completed at last sync
        }
        __syncthreads();

        // --- 4. score[s] = h . keys[b,s,:]  (8 partial threads per s) ---
        if (tid < 248) {
            int s = tid >> 3, p = tid & 7;
            const float* hp = hS + p * 32;
            const float* kp = keysb + s * NU + p * 32;
            float sp = 0.0f;
#pragma unroll 8
            for (int i = 0; i < 32; ++i) sp += hp[i] * kp[i];
            spS[tid] = sp;
        }
        __syncthreads();
        if (tid < NS) {
            float sc = 0.0f;
#pragma unroll
            for (int p = 0; p < 8; ++p) sc += spS[tid * 8 + p];
            scS[tid] = sc;
        }
        __syncthreads();

        // --- 5. softmax + context (redundant per-thread max/sum, no syncs) ---
        float mx = scS[0];
#pragma unroll
        for (int s = 1; s < NS; ++s) mx = fmaxf(mx, scS[s]);
        float sumE = 0.0f, ctx = 0.0f;
#pragma unroll 4
        for (int s = 0; s < NS; ++s) {
            float e = __expf(scS[s] - mx);
            sumE += e;
            ctx += e * memb[s * NU + tid];
        }
        ctx /= sumE;
        ctxS[tid] = ctx;
        __syncthreads();

        // --- 6. attn = concat(h, context) @ W_attn ---
        float a_acc = 0.0f;
#pragma unroll 8
        for (int k = 0; k < NU; ++k) a_acc += hS[k] * W_attn[k * NU + tid];
#pragma unroll 8
        for (int k = 0; k < NU; ++k) a_acc += ctxS[k] * W_attn[(NU + k) * NU + tid];
        attn_reg = a_acc;
        attn_all[((size_t)b * NT + t) * NU + tid] = a_acc;
        // no trailing sync needed: next phase-1 only writes cinS, which
        // phase 5/6 stragglers never read; phase-1's own sync orders phase 2.
    }
}

// ---------------------------------------------------------------------------
// out[m, n] = attn_all[m, :] @ W_fc[:, n] + b_fc[n],  m = b*NT + t
// M=1920, N=32000, K=256.  128x128 tile, 8x8 per thread (split 4+4 at +64
// so LDS reads are <=2-way bank aliased), KC=32 chunks.
// ---------------------------------------------------------------------------
constexpr int BM = 128, BN = 128, KC = 32, KTOT = NU;

__global__ __launch_bounds__(256) void out_gemm(
    const float* __restrict__ A,    // [1920,256]
    const float* __restrict__ Wfc,  // [256,32000]
    const float* __restrict__ bfc,  // [32000]
    float* __restrict__ out)        // [1920,32000]
{
    const int n0 = blockIdx.x * BN;
    const int m0 = blockIdx.y * BM;
    const int tid = threadIdx.x;
    const int tx = tid & 15, ty = tid >> 4;

    __shared__ float As[KC][BM + 4];  // +4 keeps 16B alignment, breaks banks
    __shared__ float Bs[KC][BN];

    float acc[2][4][2][4] = {};

    const int kq = tid & 7,  r0 = tid >> 3;   // A staging: 8 k-quads x 32 rows
    const int nq = tid & 31, kr0 = tid >> 5;  // B staging: 32 n-quads x 8 k-rows

    for (int kb = 0; kb < KTOT; kb += KC) {
#pragma unroll
        for (int p = 0; p < 4; ++p) {
            int r = r0 + p * 32;
            float4 av = *(const float4*)(A + (size_t)(m0 + r) * KTOT + kb + kq * 4);
            As[kq * 4 + 0][r] = av.x;
            As[kq * 4 + 1][r] = av.y;
            As[kq * 4 + 2][r] = av.z;
            As[kq * 4 + 3][r] = av.w;
        }
#pragma unroll
        for (int p = 0; p < 4; ++p) {
            int kr = kr0 + p * 8;
            *(float4*)&Bs[kr][nq * 4] =
                *(const float4*)(Wfc + (size_t)(kb + kr) * NV + n0 + nq * 4);
        }
        __syncthreads();

#pragma unroll 4
        for (int k = 0; k < KC; ++k) {
            float4 a0 = *(const float4*)&As[k][ty * 4];
            float4 a1 = *(const float4*)&As[k][64 + ty * 4];
            float4 b0 = *(const float4*)&Bs[k][tx * 4];
            float4 b1 = *(const float4*)&Bs[k][64 + tx * 4];
            float am[2][4] = {{a0.x, a0.y, a0.z, a0.w}, {a1.x, a1.y, a1.z, a1.w}};
            float bv[2][4] = {{b0.x, b0.y, b0.z, b0.w}, {b1.x, b1.y, b1.z, b1.w}};
#pragma unroll
            for (int im = 0; im < 2; ++im)
#pragma unroll
                for (int i = 0; i < 4; ++i)
#pragma unroll
                    for (int jn = 0; jn < 2; ++jn)
#pragma unroll
                        for (int j = 0; j < 4; ++j)
                            acc[im][i][jn][j] += am[im][i] * bv[jn][j];
        }
        __syncthreads();
    }

    float4 bias[2];
    bias[0] = *(const float4*)(bfc + n0 + tx * 4);
    bias[1] = *(const float4*)(bfc + n0 + 64 + tx * 4);
#pragma unroll
    for (int im = 0; im < 2; ++im)
#pragma unroll
        for (int i = 0; i < 4; ++i) {
            int m = m0 + im * 64 + ty * 4 + i;
#pragma unroll
            for (int jn = 0; jn < 2; ++jn) {
                float4 v;
                float4 bb = bias[jn];
                v.x = acc[im][i][jn][0] + bb.x;
                v.y = acc[im][i][jn][1] + bb.y;
                v.z = acc[im][i][jn][2] + bb.z;
                v.w = acc[im][i][jn][3] + bb.w;
                *(float4*)(out + (size_t)m * NV + n0 + jn * 64 + tx * 4) = v;
            }
        }
}

// ---------------------------------------------------------------------------
extern "C" void kernel_launch(void* const* d_in, const int* in_sizes, int n_in,
                              void* d_out, int out_size, void* d_ws, size_t ws_size,
                              hipStream_t stream) {
    const int*   inputs   = (const int*)  d_in[0];
    const float* memory   = (const float*)d_in[1];
    const float* sample_h = (const float*)d_in[2];
    const float* sample_c = (const float*)d_in[3];
    const float* emb      = (const float*)d_in[4];
    const float* W_k      = (const float*)d_in[5];
    const float* W_r      = (const float*)d_in[6];
    const float* b_lstm   = (const float*)d_in[7];
    const float* W_mem    = (const float*)d_in[8];
    const float* W_attn   = (const float*)d_in[9];
    const float* W_fc     = (const float*)d_in[10];
    const float* b_fc     = (const float*)d_in[11];
    float* out = (float*)d_out;

    // workspace: keys [NB*NS*NU] then attn_all [NB*NT*NU]  (~4 MB total)
    float* keys = (float*)d_ws;
    float* attn_all = keys + (size_t)NB * NS * NU;

    keys_kernel<<<(NB * NS) / 8, 256, 0, stream>>>(memory, W_mem, keys);
    recurrence_kernel<<<NB, 256, 0, stream>>>(inputs, memory, sample_h, sample_c,
                                              emb, W_k, W_r, b_lstm, W_attn,
                                              keys, attn_all);
    out_gemm<<<dim3(NV / BN, (NB * NT) / BM), 256, 0, stream>>>(attn_all, W_fc,
                                                                b_fc, out);
}